// Round 6
// baseline (1671.487 us; speedup 1.0000x reference)
//
#include <hip/hip_runtime.h>

#define E_    300
#define H2_   256
#define B_    64
#define S_    256
#define G_    (S_*B_)     // 16384
#define GATES (4*H2_)     // 1024
#define NS    8           // unit slices per direction

// ---------------- prep: pack whh for per-thread f4 runs + bias sums ----------------
// wpack[((d*8+s)*512 + t)*64 + gt*16 + kk] = whh_d[gt*256 + s*32 + (t>>4)][ (t&15)*16 + kk ]
__global__ void prep_kernel(const float* __restrict__ whh_f, const float* __restrict__ whh_b,
                            const float* __restrict__ bih_f, const float* __restrict__ bhh_f,
                            const float* __restrict__ bih_b, const float* __restrict__ bhh_b,
                            float* __restrict__ wpack, float* __restrict__ bsum) {
    int idx = blockIdx.x * blockDim.x + threadIdx.x;
    if (idx < 2 * 8 * 512 * 64) {              // 524288
        int d  = idx >> 18;
        int s  = (idx >> 15) & 7;
        int t  = (idx >> 6) & 511;
        int e  = idx & 63;
        int gt = e >> 4, kk = e & 15;
        int u  = t >> 4, cc = t & 15;
        int row = gt * 256 + s * 32 + u;
        int col = cc * 16 + kk;
        const float* w = d ? whh_b : whh_f;    // (1024, 256) row-major
        wpack[idx] = w[row * H2_ + col];
    }
    if (idx < 2 * GATES) {
        int d = idx >> 10, j = idx & 1023;
        bsum[idx] = d ? (bih_b[j] + bhh_b[j]) : (bih_f[j] + bhh_f[j]);
    }
}

// ---------------- input projection GEMM (unchanged) ----------------
__global__ __launch_bounds__(256) void xproj_kernel(
    const int* __restrict__ sent, const float* __restrict__ emb,
    const float* __restrict__ wih_f, const float* __restrict__ wih_b,
    const float* __restrict__ bsum, float* __restrict__ xp) {
    __shared__ float As[128 * 21];
    __shared__ float Bs[20 * 64];
    __shared__ int   toks[128];
    int gt = blockIdx.x, jt = blockIdx.y, d = blockIdx.z;
    const float* wih = d ? wih_b : wih_f;       // (1024, 300)
    int tid = threadIdx.x;
    int g0 = gt * 128, j0 = jt * 64;
    if (tid < 128) toks[tid] = sent[g0 + tid];
    __syncthreads();

    int ty = tid >> 4, tx = tid & 15;
    float acc[8][4];
    float4 bv = *(const float4*)&bsum[d * 1024 + j0 + tx * 4];
    #pragma unroll
    for (int i = 0; i < 8; i++) { acc[i][0] = bv.x; acc[i][1] = bv.y; acc[i][2] = bv.z; acc[i][3] = bv.w; }

    for (int kt = 0; kt < 15; kt++) {
        int k0 = kt * 20;
        #pragma unroll
        for (int l = 0; l < 10; l++) {
            int e = l * 256 + tid; int i = e / 20, k = e % 20;
            As[i * 21 + k] = emb[(long)toks[i] * E_ + k0 + k];
        }
        #pragma unroll
        for (int l = 0; l < 5; l++) {
            int e = l * 256 + tid; int k = e >> 6, j = e & 63;
            Bs[k * 64 + j] = wih[(j0 + j) * E_ + k0 + k];
        }
        __syncthreads();
        #pragma unroll
        for (int k = 0; k < 20; k++) {
            float4 b4 = *(const float4*)&Bs[k * 64 + tx * 4];
            #pragma unroll
            for (int i = 0; i < 8; i++) {
                float a = As[(ty * 8 + i) * 21 + k];
                acc[i][0] += a * b4.x; acc[i][1] += a * b4.y;
                acc[i][2] += a * b4.z; acc[i][3] += a * b4.w;
            }
        }
        __syncthreads();
    }
    #pragma unroll
    for (int i = 0; i < 8; i++) {
        float4 o; o.x = acc[i][0]; o.y = acc[i][1]; o.z = acc[i][2]; o.w = acc[i][3];
        *(float4*)&xp[((long)d * G_ + g0 + ty * 8 + i) * 1024 + j0 + tx * 4] = o;
    }
}

// ---------------- LSTM: 256 blocks = 32 groups (dir x 4-batch) x 8 unit-slices ----------------
// Thread (u,cc): 4 gates x 16 cols x 4 batches in VGPRs. cc-reduction = in-register
// shfl_xor butterfly over the 16-lane group (transposes to lane cc = (gate cc>>2, batch cc&3)).
// LDS padded to 87KB to force 1 block/CU (256 blocks -> all 256 CUs).
__global__ __launch_bounds__(512, 2) void lstm_kernel(
    const float* __restrict__ xp, const float* __restrict__ wpack,
    const float* __restrict__ h0, const float* __restrict__ c0,
    float* __restrict__ hcat, unsigned long long* __restrict__ mbox) {
    __shared__ float h_cur[21760];   // first 1280 used as [4][320]; rest pads LDS -> 1 block/CU

    int t = threadIdx.x;
    int bid = blockIdx.x;
    int x = bid & 7, rest = bid >> 3;
    int s = rest & 7, Ghi = rest >> 3;
    int G = Ghi * 8 + x;               // slices of G share bid&7 (XCD colocation)
    int d = G >> 4, bg = G & 15;
    int u = t >> 4, cc = t & 15;
    int gt_m = cc >> 2, j_m = cc & 3;  // post-butterfly identity of this lane

    // weights -> VGPRs (16 f4 per thread)
    float4 w[4][4];
    const float4* wbase = (const float4*)(wpack + (size_t)((d * 8 + s) * 512 + t) * 64);
    #pragma unroll
    for (int gt = 0; gt < 4; gt++)
        #pragma unroll
        for (int k4 = 0; k4 < 4; k4++)
            w[gt][k4] = wbase[gt * 4 + k4];

    for (int e = t; e < 1024; e += 512) {
        int j = e >> 8, k = e & 255;
        h_cur[j * 320 + (k >> 4) * 20 + (k & 15)] = h0[(d * B_ + bg * 4 + j) * H2_ + k];
    }
    float c = 0.f;
    if (cc < 4) c = c0[(d * B_ + bg * 4 + cc) * H2_ + s * 32 + u];

    unsigned long long* mb_out = mbox + (size_t)(G * NS + s) * 256;
    const size_t xbase = (size_t)d * G_ * 1024;
    __syncthreads();

    for (int step = 0; step < S_; step++) {
        int sidx = d ? (255 - step) : step;
        // prefetch this lane's xp scalar (row gt_m*256+s*32+u, batch j_m)
        float xv = xp[xbase + (size_t)(sidx * 64 + bg * 4 + j_m) * 1024
                      + gt_m * 256 + s * 32 + u];

        // ---- register-blocked partial GEMV ----
        float acc[4][4];
        #pragma unroll
        for (int gt = 0; gt < 4; gt++)
            #pragma unroll
            for (int j = 0; j < 4; j++) acc[gt][j] = 0.f;
        #pragma unroll
        for (int j = 0; j < 4; j++) {
            const float* hb = &h_cur[j * 320 + cc * 20];
            #pragma unroll
            for (int k4 = 0; k4 < 4; k4++) {
                float4 h4 = *(const float4*)(hb + k4 * 4);
                #pragma unroll
                for (int gt = 0; gt < 4; gt++) {
                    acc[gt][j] += w[gt][k4].x * h4.x + w[gt][k4].y * h4.y
                                + w[gt][k4].z * h4.z + w[gt][k4].w * h4.w;
                }
            }
        }
        __syncthreads();   // all h_cur reads done before any write below

        // ---- in-register butterfly reduction+transpose over the 16-lane group ----
        float a_[16];
        #pragma unroll
        for (int gt = 0; gt < 4; gt++)
            #pragma unroll
            for (int j = 0; j < 4; j++) a_[gt * 4 + j] = acc[gt][j];
        bool p0 = (cc & 1), p1 = (cc & 2), p2 = (cc & 4), p3 = (cc & 8);
        float b_[8];
        #pragma unroll
        for (int m = 0; m < 8; m++) {
            float lo = a_[2 * m], hi = a_[2 * m + 1];
            b_[m] = (p0 ? hi : lo) + __shfl_xor(p0 ? lo : hi, 1);
        }
        float c_[4];
        #pragma unroll
        for (int m = 0; m < 4; m++) {
            float lo = b_[2 * m], hi = b_[2 * m + 1];
            c_[m] = (p1 ? hi : lo) + __shfl_xor(p1 ? lo : hi, 2);
        }
        float d_[2];
        #pragma unroll
        for (int m = 0; m < 2; m++) {
            float lo = c_[2 * m], hi = c_[2 * m + 1];
            d_[m] = (p2 ? hi : lo) + __shfl_xor(p2 ? lo : hi, 4);
        }
        float ev = (p3 ? d_[1] : d_[0]) + __shfl_xor(p3 ? d_[0] : d_[1], 8);
        ev += xv;   // lane cc now holds gate (cc>>2) preact for (unit u, batch cc&3)

        // gather f,g,o into the i-lanes (cc<4)
        int base = t & ~15;
        float fv = __shfl(ev, base + 4 + (t & 3));
        float gv = __shfl(ev, base + 8 + (t & 3));
        float ov = __shfl(ev, base + 12 + (t & 3));

        if (cc < 4) {
            float si = 1.f / (1.f + __expf(-ev));
            float sf = 1.f / (1.f + __expf(-fv));
            float so = 1.f / (1.f + __expf(-ov));
            float tg = tanhf(gv);
            c = sf * c + si * tg;
            float h = so * tanhf(c);
            int k = s * 32 + u;
            h_cur[cc * 320 + (k >> 4) * 20 + (k & 15)] = h;
            union { float f; unsigned u32; } cv; cv.f = h;
            __hip_atomic_store(&mb_out[(step & 1) * 128 + cc * 32 + u],
                ((unsigned long long)(unsigned)(step + 1) << 32) | cv.u32,
                __ATOMIC_RELAXED, __HIP_MEMORY_SCOPE_AGENT);
            hcat[(size_t)(sidx * 64 + bg * 4 + cc) * 512 + d * 256 + k] = h;
        }

        // ---- ingest 7 peer slices (896 values over 512 threads) ----
        for (int vv = t; vv < 896; vv += 512) {
            int spr = vv >> 7;
            int sp = spr + (spr >= s ? 1 : 0);
            int rem = vv & 127;
            int j = rem >> 5, uu = rem & 31;
            unsigned long long* ad =
                mbox + (size_t)(G * NS + sp) * 256 + (step & 1) * 128 + rem;
            unsigned long long val;
            do {
                val = __hip_atomic_load(ad, __ATOMIC_RELAXED, __HIP_MEMORY_SCOPE_AGENT);
            } while ((unsigned)(val >> 32) != (unsigned)(step + 1));
            union { unsigned u32; float f; } cv; cv.u32 = (unsigned)val;
            int k = sp * 32 + uu;
            h_cur[j * 320 + (k >> 4) * 20 + (k & 15)] = cv.f;
        }
        __syncthreads();
    }
}

// ---------------- feats (unchanged) ----------------
__global__ void feats_kernel(const float* __restrict__ hcat, const float* __restrict__ Wout,
                             const float* __restrict__ bout, float* __restrict__ feats) {
    int tid = threadIdx.x; int w = tid >> 6, l = tid & 63;
    int g = blockIdx.x * 4 + w;
    float r[8];
    #pragma unroll
    for (int m = 0; m < 8; m++) r[m] = hcat[(long)g * 512 + m * 64 + l];
    #pragma unroll
    for (int tt = 0; tt < 10; tt++) {
        float a = 0.f;
        #pragma unroll
        for (int m = 0; m < 8; m++) a += r[m] * Wout[tt * 512 + m * 64 + l];
        #pragma unroll
        for (int off = 32; off > 0; off >>= 1) a += __shfl_down(a, off);
        if (l == 0) feats[g * 10 + tt] = a + bout[tt];
    }
}

// ---------------- Viterbi (unchanged) ----------------
__global__ void viterbi_kernel(const float* __restrict__ feats, const float* __restrict__ trans,
                               float* __restrict__ out) {
    __shared__ unsigned char bp[256 * 16];
    int l = threadIdx.x; int b = blockIdx.x;
    float trrow[10];
    #pragma unroll
    for (int p = 0; p < 10; p++) trrow[p] = (l < 10) ? trans[l * 10 + p] : 0.f;
    float tr_stop = (l < 10) ? trans[90 + l] : -3e38f;
    float fv = (l == 8) ? 0.f : -10000.f;

    for (int s = 0; s < 256; s++) {
        float m = -3e38f; int arg = 0;
        #pragma unroll
        for (int p = 0; p < 10; p++) {
            float v = __shfl(fv, p) + trrow[p];
            if (v > m) { m = v; arg = p; }
        }
        float ft = (l < 10) ? feats[((long)b * 256 + s) * 10 + l] : 0.f;
        fv = m + ft;
        if (l < 10) bp[s * 16 + l] = (unsigned char)arg;
    }
    __syncthreads();
    float term = fv + tr_stop;
    float best = -3e38f; int bt = 0;
    #pragma unroll
    for (int p = 0; p < 10; p++) {
        float v = __shfl(term, p);
        if (v > best) { best = v; bt = p; }
    }
    if (l == 0) {
        out[b] = best;
        int cur = bt;
        out[64 + b * 256 + 255] = (float)cur;
        for (int s = 254; s >= 0; s--) {
            cur = bp[(s + 1) * 16 + cur];
            out[64 + b * 256 + s] = (float)cur;
        }
    }
}

extern "C" void kernel_launch(void* const* d_in, const int* in_sizes, int n_in,
                              void* d_out, int out_size, void* d_ws, size_t ws_size,
                              hipStream_t stream) {
    const int*   sent  = (const int*)  d_in[0];
    const float* emb   = (const float*)d_in[1];
    const float* wih_f = (const float*)d_in[2];
    const float* whh_f = (const float*)d_in[3];
    const float* bih_f = (const float*)d_in[4];
    const float* bhh_f = (const float*)d_in[5];
    const float* wih_b = (const float*)d_in[6];
    const float* whh_b = (const float*)d_in[7];
    const float* bih_b = (const float*)d_in[8];
    const float* bhh_b = (const float*)d_in[9];
    const float* Wout  = (const float*)d_in[10];
    const float* bout  = (const float*)d_in[11];
    const float* h0    = (const float*)d_in[12];
    const float* c0    = (const float*)d_in[13];
    const float* trans = (const float*)d_in[14];

    float* ws    = (float*)d_ws;
    float* xp    = ws;                  // [2][16384][1024] = 33,554,432 f
    float* hcat  = ws + 33554432;       // [16384][512]     =  8,388,608 f
    float* wpack = ws + 41943040;       // [2][8][512][64]  =    524,288 f
    float* bsum  = ws + 42467328;       // [2][1024]        =      2,048 f
    unsigned long long* mbox = (unsigned long long*)(ws + 42469376); // 65,536 u64
    float* feats = ws;                  // aliases xp (dead after lstm)
    float* out   = (float*)d_out;

    hipLaunchKernelGGL(prep_kernel, dim3(2048), dim3(256), 0, stream,
                       whh_f, whh_b, bih_f, bhh_f, bih_b, bhh_b, wpack, bsum);
    hipLaunchKernelGGL(xproj_kernel, dim3(128, 16, 2), dim3(256), 0, stream,
                       sent, emb, wih_f, wih_b, bsum, xp);

    void* lstm_args[] = { (void*)&xp, (void*)&wpack, (void*)&h0, (void*)&c0,
                          (void*)&hcat, (void*)&mbox };
    hipLaunchCooperativeKernel((const void*)lstm_kernel, dim3(256), dim3(512),
                               lstm_args, 0, stream);

    hipLaunchKernelGGL(feats_kernel, dim3(4096), dim3(256), 0, stream,
                       hcat, Wout, bout, feats);
    hipLaunchKernelGGL(viterbi_kernel, dim3(64), dim3(64), 0, stream,
                       feats, trans, out);
}